// Round 4
// baseline (137.243 us; speedup 1.0000x reference)
//
#include <hip/hip_runtime.h>
#include <hip/hip_cooperative_groups.h>
#include <math.h>

namespace cg = cooperative_groups;

#define BB 2
#define NN 8192
#define NB 256           // cooperative grid blocks (1/CU guaranteed resident)
#define NT 256

// ws layout (floats):
#define ACC_OFF 0
#define CNT_OFF 64
#define CDATA_OFF 80
#define PM_OFF (CDATA_OFF + BB * NN * 4)
#define PARTIAL_OFF (PM_OFF + BB * NN)
// partial: [jb<32][b*NN+i][3] floats = 6.3 MB

// acc layout per sample:
// 0 ref_sum, 1 con_sum, 2 n_pred, 3 spx, 4 spy, 5 spz, 6 n_gt, 7 bm_sum,
// 8..13 cov(xx,xy,xz,yy,yz,zz), 14 sum_dm, 15 sum_d2m, 16 max_dm(bits),
// 17 smooth_num, 18 smooth_den

__device__ __forceinline__ float wave_sum(float v) {
#pragma unroll
    for (int o = 32; o > 0; o >>= 1) v += __shfl_xor(v, o, 64);
    return v;
}

__device__ __forceinline__ void wave_atomic_add(float* addr, float v) {
    v = wave_sum(v);
    if ((threadIdx.x & 63) == 0) atomicAdd(addr, v);
}

__device__ __forceinline__ void wave_atomic_max_nonneg(float* addr, float v) {
#pragma unroll
    for (int o = 32; o > 0; o >>= 1) v = fmaxf(v, __shfl_xor(v, o, 64));
    if ((threadIdx.x & 63) == 0) atomicMax((unsigned int*)addr, __float_as_uint(v));
}

__global__ void __launch_bounds__(NT) mega(const float* __restrict__ logits, const float* __restrict__ olog,
                                           const float* __restrict__ h, const int* __restrict__ tgt,
                                           const float* __restrict__ pts, float* __restrict__ ws,
                                           float* __restrict__ out) {
    cg::grid_group gg = cg::this_grid();
    const int tid = blockIdx.x * NT + threadIdx.x;
    const int lane = threadIdx.x & 63;
    unsigned int* cnts = (unsigned int*)(ws + CNT_OFF);
    float4* cdata = (float4*)(ws + CDATA_OFF);

    // ---- phase 0: zero accumulators + compaction counters ----
    if (tid < BB * 32) ws[ACC_OFF + tid] = 0.f;
    if (tid < BB) cnts[tid] = 0u;
    gg.sync();

    // ---- phase 1: per-point pass + boundary compaction ----
    if (tid < BB * NN) {
        int gid = tid;
        int b = gid / NN;

        const float* L = logits + (size_t)gid * 3;
        float l0 = L[0], l1 = L[1], l2 = L[2];
        const float* O = olog + (size_t)gid * 3;
        float o0 = O[0], o1 = O[1], o2 = O[2];
        float hp = h[gid];
        int t = tgt[gid];
        const float* P = pts + (size_t)gid * 3;
        float px = P[0], py = P[1], pz = P[2];

        float m = fmaxf(l0, fmaxf(l1, l2));
        float e0 = expf(l0 - m), e1 = expf(l1 - m), e2 = expf(l2 - m);
        float s = e0 + e1 + e2;
        float inv = 1.f / s;
        float p0 = e0 * inv, p1 = e1 * inv, p2 = e2 * inv;
        float ls = logf(s);
        float lt = (t == 0) ? l0 : ((t == 1) ? l1 : l2);
        float nll = -(lt - m - ls);

        float mo = fmaxf(o0, fmaxf(o1, o2));
        float f0 = expf(o0 - mo), f1 = expf(o1 - mo), f2 = expf(o2 - mo);
        float so = 1.f / (f0 + f1 + f2);
        float q0 = f0 * so, q1 = f1 * so, q2 = f2 * so;

        float con = (p0 - q0) * (p0 - q0) + (p1 - q1) * (p1 - q1) + (p2 - q2) * (p2 - q2);

        float bm = (hp > 0.3f && hp < 0.7f) ? 1.f : 0.f;
        float refc = nll * (1.f + bm);
        float pred = (l2 > l0 && l2 > l1) ? 1.f : 0.f;
        float gt = (t == 2) ? 1.f : 0.f;

        // wave-aggregated compaction: one atomic per wave
        unsigned long long mask = __ballot(bm > 0.f);
        unsigned int base = 0;
        if (lane == 0 && mask)
            base = atomicAdd(cnts + b, (unsigned int)__popcll(mask));
        base = __shfl((int)base, 0, 64);
        if (bm > 0.f) {
            unsigned int idx = base + __popcll(mask & ((1ull << lane) - 1ull));
            cdata[(size_t)b * NN + idx] = make_float4(px, py, pz, p2);
        }
        ws[PM_OFF + gid] = pred;

        float* a = ws + ACC_OFF + b * 32;
        wave_atomic_add(a + 0, refc);
        wave_atomic_add(a + 1, con);
        wave_atomic_add(a + 2, pred);
        wave_atomic_add(a + 3, pred * px);
        wave_atomic_add(a + 4, pred * py);
        wave_atomic_add(a + 5, pred * pz);
        wave_atomic_add(a + 6, gt);
        wave_atomic_add(a + 7, bm);
    }
    gg.sync();

    // ---- phase 2: covariance + distance stats (needs center) ----
    if (tid < BB * NN) {
        int gid = tid;
        int b = gid / NN;
        float* a = ws + ACC_OFF + b * 32;

        float n = a[2];
        float nz = fmaxf(n, 1.f);
        float cx = a[3] / nz, cy = a[4] / nz, cz = a[5] / nz;

        const float* P = pts + (size_t)gid * 3;
        float dx = P[0] - cx, dy = P[1] - cy, dz = P[2] - cz;
        float mM = ws[PM_OFF + gid];

        float mx = dx * mM, my = dy * mM, mz = dz * mM;
        float d = sqrtf(dx * dx + dy * dy + dz * dz + 1e-12f);
        float dm = d * mM;

        wave_atomic_add(a + 8,  mx * mx);
        wave_atomic_add(a + 9,  mx * my);
        wave_atomic_add(a + 10, mx * mz);
        wave_atomic_add(a + 11, my * my);
        wave_atomic_add(a + 12, my * mz);
        wave_atomic_add(a + 13, mz * mz);
        wave_atomic_add(a + 14, dm);
        wave_atomic_add(a + 15, d * dm);
        wave_atomic_max_nonneg(a + 16, dm);
    }

    // ---- phase 3: pairwise ball-query over compacted boundary points ----
    {
        int M0 = (int)cnts[0], M1 = (int)cnts[1];
        int JB0 = (M0 + 255) >> 8, JB1 = (M1 + 255) >> 8;
        int t0 = JB0 * JB0;
        int total = t0 + JB1 * JB1;
        __shared__ float4 sj[256];

        for (int tile = blockIdx.x; tile < total; tile += gridDim.x) {
            int b, rel, JB, M;
            if (tile < t0) { b = 0; rel = tile; JB = JB0; M = M0; }
            else           { b = 1; rel = tile - t0; JB = JB1; M = M1; }
            int ib = rel / JB, jb = rel % JB;

            const float4* cd = cdata + (size_t)b * NN;
            int i = ib * 256 + (int)threadIdx.x;
            bool act = i < M;
            float4 me = cd[act ? i : 0];
            float xi = act ? me.x : 1e9f;

            __syncthreads();
            int j = jb * 256 + (int)threadIdx.x;
            sj[threadIdx.x] = (j < M) ? cd[j] : make_float4(1e9f, 1e9f, 1e9f, 0.f);
            __syncthreads();

            float cnt = 0.f, s1 = 0.f, s2 = 0.f;
#pragma unroll 8
            for (int k = 0; k < 256; k++) {
                float4 v = sj[k];
                float dx = xi - v.x, dy = me.y - v.y, dz = me.z - v.z;
                float d2 = dx * dx + dy * dy + dz * dz;
                float wv = (d2 < 0.0025f) ? 1.f : 0.f;     // branchless
                cnt += wv; s1 += wv * v.w; s2 += wv * (v.w * v.w);
            }
            float* p = ws + PARTIAL_OFF + ((size_t)jb * (BB * NN) + (size_t)b * NN + i) * 3;
            p[0] = cnt; p[1] = s1; p[2] = s2;
        }
    }
    gg.sync();

    // ---- phase 4: per-i variance + reduce ----
    if (tid < BB * NN) {
        int b = tid / NN, i = tid % NN;
        int M = (int)cnts[b];
        int JB = (M + 255) >> 8;
        float cnt = 0.f, s1 = 0.f, s2 = 0.f;
        if (i < M) {
            for (int jb = 0; jb < JB; jb++) {
                const float* p = ws + PARTIAL_OFF + ((size_t)jb * (BB * NN) + (size_t)b * NN + i) * 3;
                cnt += p[0]; s1 += p[1]; s2 += p[2];
            }
        }
        float var = (s2 - s1 * s1 / fmaxf(cnt, 1.f)) / fmaxf(cnt - 1.f, 1.f);
        float valid = (i < M && cnt > 1.f) ? 1.f : 0.f;
        float* a = ws + ACC_OFF + b * 32;
        wave_atomic_add(a + 17, var * valid);
        wave_atomic_add(a + 18, valid);
    }
    gg.sync();

    // ---- phase 5: scalar finalize ----
    if (tid == 0) {
        double tot = 0.0;
        for (int b = 0; b < BB; b++) {
            const float* a = ws + ACC_OFF + b * 32;
            double refm = (double)a[0] / NN;
            double conm = (double)a[1] / (NN * 3);
            double n = a[2];
            double nz = fmax(n, 1.0);

            double shape = 0.0;
            if (n >= 10.0) {
                double cxx = a[8] / nz, cxy = a[9] / nz, cxz = a[10] / nz;
                double cyy = a[11] / nz, cyz = a[12] / nz, czz = a[13] / nz;
                double q = (cxx + cyy + czz) / 3.0;
                double p1 = cxy * cxy + cxz * cxz + cyz * cyz;
                double p2 = (cxx - q) * (cxx - q) + (cyy - q) * (cyy - q) + (czz - q) * (czz - q) + 2.0 * p1;
                double p = sqrt(fmax(p2, 0.0) / 6.0);
                double ev0, ev1, ev2;
                if (p < 1e-30) { ev0 = ev1 = ev2 = q; }
                else {
                    double b00 = (cxx - q) / p, b11 = (cyy - q) / p, b22 = (czz - q) / p;
                    double b01 = cxy / p, b02 = cxz / p, b12 = cyz / p;
                    double det = b00 * (b11 * b22 - b12 * b12)
                               - b01 * (b01 * b22 - b12 * b02)
                               + b02 * (b01 * b12 - b11 * b02);
                    double r = det / 2.0;
                    r = fmin(1.0, fmax(-1.0, r));
                    double phi = acos(r) / 3.0;
                    double e1 = q + 2.0 * p * cos(phi);
                    double e3 = q + 2.0 * p * cos(phi + 2.0943951023931953);
                    double e2 = 3.0 * q - e1 - e3;
                    ev2 = e1; ev1 = e2; ev0 = e3;
                }
                double aa = ev2 + 1e-8;
                double r1 = ev1 / aa - 1.0, r0 = ev0 / aa - 1.0;
                shape = r1 * r1 + r0 * r0;
            }

            double sdm = a[14], sd2m = a[15], maxd = a[16];
            double var = (sd2m - sdm * sdm / nz) / fmax(n - 1.0, 1.0);
            double conn = (n >= 5.0) ? var / (maxd + 1e-8) : 0.0;

            double sm = (a[7] >= 5.0) ? (double)a[17] / fmax((double)a[18], 1.0) : 0.0;

            double pv = a[2], gv = a[6];
            double vol = (pv - gv) * (pv - gv);
            double rel = fabs(pv - gv) / fmax(gv, 1.0);
            double size = (gv > 0.0) ? vol + 0.5 * rel : vol;

            tot += 0.3 * refm + 0.2 * conm + 0.5 * shape + 0.3 * sm + 0.8 * size + 0.6 * conn;
        }
        out[0] = (float)(tot / BB);
    }
}

extern "C" void kernel_launch(void* const* d_in, const int* in_sizes, int n_in,
                              void* d_out, int out_size, void* d_ws, size_t ws_size,
                              hipStream_t stream) {
    const float* logits = (const float*)d_in[0];
    const float* olog   = (const float*)d_in[1];
    const float* h      = (const float*)d_in[2];
    const int*   tgt    = (const int*)d_in[3];
    const float* pts    = (const float*)d_in[4];
    float* out = (float*)d_out;
    float* ws  = (float*)d_ws;

    void* args[7] = { (void*)&logits, (void*)&olog, (void*)&h, (void*)&tgt,
                      (void*)&pts, (void*)&ws, (void*)&out };
    hipLaunchCooperativeKernel(mega, dim3(NB), dim3(NT), args, 0u, stream);
}

// Round 5
// 60.036 us; speedup vs baseline: 2.2860x; 2.2860x over previous
//
#include <hip/hip_runtime.h>
#include <math.h>

#define BB 2
#define NN 8192
#define NT 256
#define MAXJB 32            // ceil(NN/256) worst-case j-tiles per sample

// ws layout (floats):
#define ACC_OFF 0           // BB*32 floats
#define CNT_OFF 64          // 2 uints (compaction counters)
#define DONE_OFF 66         // 1 uint (k45 last-block counter)
#define CDATA_OFF 80        // BB*NN float4
#define PM_OFF (CDATA_OFF + BB * NN * 4)
#define PARTIAL_OFF (PM_OFF + BB * NN)   // [MAXJB][BB*NN][3] floats ~= 6.3 MB

// acc layout per sample:
// 0 ref_sum, 1 con_sum, 2 n_pred, 3 spx, 4 spy, 5 spz, 6 n_gt, 7 bm_sum,
// 8..13 cov(xx,xy,xz,yy,yz,zz), 14 sum_dm, 15 sum_d2m, 16 max_dm(bits),
// 17 smooth_num, 18 smooth_den

__device__ __forceinline__ float wave_sum(float v) {
#pragma unroll
    for (int o = 32; o > 0; o >>= 1) v += __shfl_xor(v, o, 64);
    return v;
}

__device__ __forceinline__ void wave_atomic_add(float* addr, float v) {
    v = wave_sum(v);
    if ((threadIdx.x & 63) == 0) atomicAdd(addr, v);
}

__device__ __forceinline__ void wave_atomic_max_nonneg(float* addr, float v) {
#pragma unroll
    for (int o = 32; o > 0; o >>= 1) v = fmaxf(v, __shfl_xor(v, o, 64));
    if ((threadIdx.x & 63) == 0) atomicMax((unsigned int*)addr, __float_as_uint(v));
}

__global__ void kz(float* ws) {
    int t = threadIdx.x;
    if (t < 80) ws[t] = 0.f;    // acc + cnts + done counter
}

__global__ void k1(const float* __restrict__ logits, const float* __restrict__ olog,
                   const float* __restrict__ h, const int* __restrict__ tgt,
                   const float* __restrict__ pts, float* __restrict__ ws) {
    int gid = blockIdx.x * NT + threadIdx.x;   // over BB*NN, blocks don't straddle b
    int b = gid / NN;
    int lane = threadIdx.x & 63;

    const float* L = logits + (size_t)gid * 3;
    float l0 = L[0], l1 = L[1], l2 = L[2];
    const float* O = olog + (size_t)gid * 3;
    float o0 = O[0], o1 = O[1], o2 = O[2];
    float hp = h[gid];
    int t = tgt[gid];
    const float* P = pts + (size_t)gid * 3;
    float px = P[0], py = P[1], pz = P[2];

    float m = fmaxf(l0, fmaxf(l1, l2));
    float e0 = expf(l0 - m), e1 = expf(l1 - m), e2 = expf(l2 - m);
    float s = e0 + e1 + e2;
    float inv = 1.f / s;
    float p0 = e0 * inv, p1 = e1 * inv, p2 = e2 * inv;
    float ls = logf(s);
    float lt = (t == 0) ? l0 : ((t == 1) ? l1 : l2);
    float nll = -(lt - m - ls);

    float mo = fmaxf(o0, fmaxf(o1, o2));
    float f0 = expf(o0 - mo), f1 = expf(o1 - mo), f2 = expf(o2 - mo);
    float so = 1.f / (f0 + f1 + f2);
    float q0 = f0 * so, q1 = f1 * so, q2 = f2 * so;

    float con = (p0 - q0) * (p0 - q0) + (p1 - q1) * (p1 - q1) + (p2 - q2) * (p2 - q2);

    float bm = (hp > 0.3f && hp < 0.7f) ? 1.f : 0.f;
    float refc = nll * (1.f + bm);
    float pred = (l2 > l0 && l2 > l1) ? 1.f : 0.f;
    float gt = (t == 2) ? 1.f : 0.f;

    // wave-aggregated compaction: one atomic per wave
    unsigned long long mask = __ballot(bm > 0.f);
    unsigned int base = 0;
    if (lane == 0 && mask)
        base = atomicAdd(((unsigned int*)(ws + CNT_OFF)) + b, (unsigned int)__popcll(mask));
    base = __shfl((int)base, 0, 64);
    if (bm > 0.f) {
        unsigned int idx = base + __popcll(mask & ((1ull << lane) - 1ull));
        ((float4*)(ws + CDATA_OFF))[(size_t)b * NN + idx] = make_float4(px, py, pz, p2);
    }
    ws[PM_OFF + gid] = pred;

    float* a = ws + ACC_OFF + b * 32;
    wave_atomic_add(a + 0, refc);
    wave_atomic_add(a + 1, con);
    wave_atomic_add(a + 2, pred);
    wave_atomic_add(a + 3, pred * px);
    wave_atomic_add(a + 4, pred * py);
    wave_atomic_add(a + 5, pred * pz);
    wave_atomic_add(a + 6, gt);
    wave_atomic_add(a + 7, bm);
}

// role-split: blocks [0,64) = cov/dist stats; blocks [64, 64+BB*1024) = pairwise tiles
__global__ void k23(const float* __restrict__ pts, float* __restrict__ ws) {
    unsigned int* cnts = (unsigned int*)(ws + CNT_OFF);
    int bid = blockIdx.x;

    if (bid < BB * NN / NT) {
        // ---- covariance + distance stats (needs center from k1) ----
        int gid = bid * NT + threadIdx.x;
        int b = gid / NN;
        float* a = ws + ACC_OFF + b * 32;

        float n = a[2];
        float nz = fmaxf(n, 1.f);
        float cx = a[3] / nz, cy = a[4] / nz, cz = a[5] / nz;

        const float* P = pts + (size_t)gid * 3;
        float dx = P[0] - cx, dy = P[1] - cy, dz = P[2] - cz;
        float mM = ws[PM_OFF + gid];

        float mx = dx * mM, my = dy * mM, mz = dz * mM;
        float d = sqrtf(dx * dx + dy * dy + dz * dz + 1e-12f);
        float dm = d * mM;

        wave_atomic_add(a + 8,  mx * mx);
        wave_atomic_add(a + 9,  mx * my);
        wave_atomic_add(a + 10, mx * mz);
        wave_atomic_add(a + 11, my * my);
        wave_atomic_add(a + 12, my * mz);
        wave_atomic_add(a + 13, mz * mz);
        wave_atomic_add(a + 14, dm);
        wave_atomic_add(a + 15, d * dm);
        wave_atomic_max_nonneg(a + 16, dm);
        return;
    }

    // ---- pairwise ball-query tile (branchless, sentinel-padded) ----
    int tile = bid - BB * NN / NT;
    int b   = tile / (MAXJB * MAXJB);
    int rel = tile % (MAXJB * MAXJB);
    int ib = rel / MAXJB, jb = rel % MAXJB;
    int M = (int)cnts[b];
    if (ib * 256 >= M || jb * 256 >= M) return;     // uniform block exit

    const float4* cd = (const float4*)(ws + CDATA_OFF) + (size_t)b * NN;
    int i = ib * 256 + (int)threadIdx.x;
    bool act = i < M;
    float4 me = cd[act ? i : 0];
    float xi = act ? me.x : 1e9f;

    __shared__ float4 sj[256];
    int j = jb * 256 + (int)threadIdx.x;
    sj[threadIdx.x] = (j < M) ? cd[j] : make_float4(1e9f, 1e9f, 1e9f, 0.f);
    __syncthreads();

    float cnt = 0.f, s1 = 0.f, s2 = 0.f;
#pragma unroll 8
    for (int k = 0; k < 256; k++) {
        float4 v = sj[k];
        float dx = xi - v.x, dy = me.y - v.y, dz = me.z - v.z;
        float d2 = dx * dx + dy * dy + dz * dz;
        float wv = (d2 < 0.0025f) ? 1.f : 0.f;      // branchless select
        cnt += wv; s1 += wv * v.w; s2 += wv * (v.w * v.w);
    }
    float* p = ws + PARTIAL_OFF + ((size_t)jb * (BB * NN) + (size_t)b * NN + i) * 3;
    p[0] = cnt; p[1] = s1; p[2] = s2;
}

__device__ __forceinline__ float acc_ld(const float* p) {
    return __hip_atomic_load(p, __ATOMIC_RELAXED, __HIP_MEMORY_SCOPE_AGENT);
}

// per-i variance reduce + last-block scalar finalize
__global__ void k45(float* __restrict__ ws, float* __restrict__ out) {
    int gid = blockIdx.x * NT + threadIdx.x;
    int b = gid / NN, i = gid % NN;
    unsigned int* cnts = (unsigned int*)(ws + CNT_OFF);
    int M = (int)cnts[b];

    float cnt = 0.f, s1 = 0.f, s2 = 0.f;
    if (i < M) {
        int JB = (M + 255) >> 8;
        for (int jb = 0; jb < JB; jb++) {
            const float* p = ws + PARTIAL_OFF + ((size_t)jb * (BB * NN) + (size_t)gid) * 3;
            cnt += p[0]; s1 += p[1]; s2 += p[2];
        }
    }
    float var = (s2 - s1 * s1 / fmaxf(cnt, 1.f)) / fmaxf(cnt - 1.f, 1.f);
    float valid = (i < M && cnt > 1.f) ? 1.f : 0.f;
    float* a0 = ws + ACC_OFF;
    wave_atomic_add(a0 + (b * 32) + 17, var * valid);
    wave_atomic_add(a0 + (b * 32) + 18, valid);

    // last-block-done finalize
    __syncthreads();
    __threadfence();
    if (threadIdx.x != 0) return;
    unsigned int old = atomicAdd((unsigned int*)(ws + DONE_OFF), 1u);
    if (old != gridDim.x - 1) return;

    double tot = 0.0;
    for (int bb = 0; bb < BB; bb++) {
        const float* a = ws + ACC_OFF + bb * 32;
        float av[19];
        for (int k = 0; k < 19; k++) av[k] = acc_ld(a + k);

        double refm = (double)av[0] / NN;
        double conm = (double)av[1] / (NN * 3);
        double n = av[2];
        double nz = fmax(n, 1.0);

        double shape = 0.0;
        if (n >= 10.0) {
            double cxx = av[8] / nz, cxy = av[9] / nz, cxz = av[10] / nz;
            double cyy = av[11] / nz, cyz = av[12] / nz, czz = av[13] / nz;
            double q = (cxx + cyy + czz) / 3.0;
            double p1 = cxy * cxy + cxz * cxz + cyz * cyz;
            double p2 = (cxx - q) * (cxx - q) + (cyy - q) * (cyy - q) + (czz - q) * (czz - q) + 2.0 * p1;
            double p = sqrt(fmax(p2, 0.0) / 6.0);
            double ev0, ev1, ev2;
            if (p < 1e-30) { ev0 = ev1 = ev2 = q; }
            else {
                double b00 = (cxx - q) / p, b11 = (cyy - q) / p, b22 = (czz - q) / p;
                double b01 = cxy / p, b02 = cxz / p, b12 = cyz / p;
                double det = b00 * (b11 * b22 - b12 * b12)
                           - b01 * (b01 * b22 - b12 * b02)
                           + b02 * (b01 * b12 - b11 * b02);
                double r = det / 2.0;
                r = fmin(1.0, fmax(-1.0, r));
                double phi = acos(r) / 3.0;
                double e1 = q + 2.0 * p * cos(phi);
                double e3 = q + 2.0 * p * cos(phi + 2.0943951023931953);
                double e2 = 3.0 * q - e1 - e3;
                ev2 = e1; ev1 = e2; ev0 = e3;
            }
            double aa = ev2 + 1e-8;
            double r1 = ev1 / aa - 1.0, r0 = ev0 / aa - 1.0;
            shape = r1 * r1 + r0 * r0;
        }

        double sdm = av[14], sd2m = av[15], maxd = av[16];
        double varc = (sd2m - sdm * sdm / nz) / fmax(n - 1.0, 1.0);
        double conn = (n >= 5.0) ? varc / (maxd + 1e-8) : 0.0;

        double sm = (av[7] >= 5.0) ? (double)av[17] / fmax((double)av[18], 1.0) : 0.0;

        double pv = av[2], gv = av[6];
        double vol = (pv - gv) * (pv - gv);
        double rel = fabs(pv - gv) / fmax(gv, 1.0);
        double size = (gv > 0.0) ? vol + 0.5 * rel : vol;

        tot += 0.3 * refm + 0.2 * conm + 0.5 * shape + 0.3 * sm + 0.8 * size + 0.6 * conn;
    }
    out[0] = (float)(tot / BB);
}

extern "C" void kernel_launch(void* const* d_in, const int* in_sizes, int n_in,
                              void* d_out, int out_size, void* d_ws, size_t ws_size,
                              hipStream_t stream) {
    const float* logits = (const float*)d_in[0];
    const float* olog   = (const float*)d_in[1];
    const float* h      = (const float*)d_in[2];
    const int*   tgt    = (const int*)d_in[3];
    const float* pts    = (const float*)d_in[4];
    float* out = (float*)d_out;
    float* ws  = (float*)d_ws;

    kz<<<1, 128, 0, stream>>>(ws);
    k1<<<BB * NN / NT, NT, 0, stream>>>(logits, olog, h, tgt, pts, ws);
    k23<<<BB * NN / NT + BB * MAXJB * MAXJB, NT, 0, stream>>>(pts, ws);
    k45<<<BB * NN / NT, NT, 0, stream>>>(ws, out);
}